// Round 2
// baseline (185.099 us; speedup 1.0000x reference)
//
#include <hip/hip_runtime.h>
#include <hip/hip_bf16.h>

#define A_DIM 200
#define F_DIM 53
#define NAF 38
#define NPHYS 15
#define R_OUT 20
#define C_OUT 1024
#define BLOCK 256
#define HPAD 40      // padded K stride of s_h in bf16 elems (zeros at 20..31)
#define MPAD 208     // padded M (13 tiles of 16)

typedef __attribute__((ext_vector_type(8))) short short8;
typedef __attribute__((ext_vector_type(4))) float floatx4;

__device__ __forceinline__ float bf_lo(uint w) { return __uint_as_float(w << 16); }
__device__ __forceinline__ float bf_hi(uint w) { return __uint_as_float(w & 0xffff0000u); }
__device__ __forceinline__ ushort f2bf(float f) {
    union { __hip_bfloat16 h; ushort u; } cv;
    cv.h = __float2bfloat16(f);   // RNE
    return cv.u;
}

__global__ __launch_bounds__(BLOCK, 4) void pggcn_kernel(
    const float* __restrict__ inputs,  // (B, 200, 53)
    const int*   __restrict__ i_s,     // (B,)
    const float* __restrict__ W_self,  // (38,20)
    const float* __restrict__ W_nei,   // (38,20)
    const float* __restrict__ b_r,     // (20,)
    const float* __restrict__ Wc,      // (20,1024)
    const float* __restrict__ bc,      // (1024,)
    const float* __restrict__ W1,      // (1024,32)
    const float* __restrict__ b1,      // (32,)
    const float* __restrict__ W5,      // (32,16)
    const float* __restrict__ b5,      // (16,)
    const float* __restrict__ W6,      // (16,1)
    const float* __restrict__ b6,      // (1,)
    const float* __restrict__ W7,      // (16,1)
    const float* __restrict__ b7,      // (1,)
    float* __restrict__ out)           // (B,16)
{
    __shared__ __align__(16) ushort s_atom[A_DIM * NAF];   // 15200 B (aliased later)
    __shared__ __align__(16) ushort s_h[MPAD * HPAD];      // 16640 B
    __shared__ float s_wself[NAF * R_OUT];                 // 3040 B
    __shared__ float s_aggp[6 * NAF];
    __shared__ float s_agg[NAF];
    __shared__ float s_hnei[R_OUT];
    __shared__ float s_phys[NPHYS];

    // aliases into s_atom (dead after h phase)
    float* s_pool = (float*)s_atom;              // 1024 f
    float* s_red  = (float*)s_atom + C_OUT;      // 256 f
    float* s_d1   = (float*)s_atom + C_OUT + 256;
    float* s_d5   = (float*)s_atom + C_OUT + 288;

    const int b    = blockIdx.x;
    const int t    = threadIdx.x;
    const int lane = t & 63;
    const int wv   = t >> 6;        // wave 0..3
    const int wb   = wv * 256;      // wave's column base in C_OUT
    const int lr   = lane & 15;     // frag row/col
    const int lg   = lane >> 4;     // frag k-group
    const int ns   = i_s[b];        // 1..199
    const float* in_b = inputs + (size_t)b * (A_DIM * F_DIM);

    // ---- B-fragments of Wc (bf16) + bias, register-resident per wave ----
    // mfma_f32_16x16x32_bf16 B layout: lane: col = lane&15, k = (lane>>4)*8 + j
    short8 bfr[16];
    float  bcv[16];
    {
        const int kbase = lg * 8;
        #pragma unroll
        for (int nt = 0; nt < 16; ++nt) {
            const int col = wb + nt * 16 + lr;
            bcv[nt] = bc[col];
            #pragma unroll
            for (int j = 0; j < 8; ++j) {
                const int k = kbase + j;
                const float v = (k < R_OUT) ? Wc[k * C_OUT + col] : 0.f;
                bfr[nt][j] = (short)f2bf(v);
            }
        }
    }

    // ---- stage W_self, physics, active atom rows (bf16) ----
    for (int i = t; i < NAF * R_OUT; i += BLOCK) s_wself[i] = W_self[i];
    if (t < NPHYS) s_phys[t] = in_b[NAF + t];
    const int tot = ns * NAF;
    for (int i = t; i < tot; i += BLOCK) {
        const int r = i / NAF;
        const int f = i - r * NAF;
        s_atom[i] = f2bf(in_b[r * F_DIM + f]);
    }
    __syncthreads();

    // ---- agg[f] = sum_{r<ns} atom[r][f] ----
    if (t < 6 * NAF) {
        const int f = t % NAF, g = t / NAF;
        float s = 0.f;
        for (int r = g; r < ns; r += 6)
            s += __uint_as_float((uint)s_atom[r * NAF + f] << 16);
        s_aggp[t] = s;
    }
    __syncthreads();
    if (t < NAF) {
        float s = 0.f;
        #pragma unroll
        for (int g = 0; g < 6; ++g) s += s_aggp[g * NAF + t];
        s_agg[t] = s;
    }
    __syncthreads();

    // ---- hnei[j] = agg @ W_nei + b_r ----
    if (t < R_OUT) {
        float s = b_r[t];
        #pragma unroll
        for (int f = 0; f < NAF; ++f) s += s_agg[f] * W_nei[f * R_OUT + t];
        s_hnei[t] = s;
    }
    __syncthreads();

    // ---- h rows -> s_h (bf16, K-padded with zeros) ----
    {
        const int j  = t % R_OUT;
        const int rg = t / R_OUT;    // 0..12 (240 active)
        if (rg < 12) {
            float wcol[NAF];
            #pragma unroll
            for (int f = 0; f < NAF; ++f) wcol[f] = s_wself[f * R_OUT + j];
            const float hn = s_hnei[j];
            for (int r = rg; r < ns; r += 12) {
                const uint* arow = (const uint*)&s_atom[r * NAF];
                float acc = hn;
                #pragma unroll
                for (int q = 0; q < NAF / 2; ++q) {
                    const uint w = arow[q];
                    acc += bf_lo(w) * wcol[2 * q];
                    acc += bf_hi(w) * wcol[2 * q + 1];
                }
                s_h[r * HPAD + j] = f2bf(fmaxf(acc, 0.f));
                if (j < 12) s_h[r * HPAD + R_OUT + j] = 0;   // zero k=20..31
            }
        }
    }
    __syncthreads();

    // ---- main: c = relu(h @ Wc + bc); pooled = sum_rows(c), MFMA path ----
    float pool[16];
    #pragma unroll
    for (int nt = 0; nt < 16; ++nt) pool[nt] = 0.f;

    const int nmt = (ns + 15) >> 4;
    for (int mt = 0; mt < nmt; ++mt) {
        // A frag: lane: row = mt*16 + (lane&15), k = (lane>>4)*8 + j
        const short8 af = *(const short8*)&s_h[(mt * 16 + lr) * HPAD + lg * 8];
        const bool full = (mt * 16 + 16 <= ns);
        const int rbase = mt * 16 + (lg << 2);
        #pragma unroll
        for (int nt = 0; nt < 16; ++nt) {
            floatx4 acc = { bcv[nt], bcv[nt], bcv[nt], bcv[nt] };
            acc = __builtin_amdgcn_mfma_f32_16x16x32_bf16(af, bfr[nt], acc, 0, 0, 0);
            if (full) {
                #pragma unroll
                for (int q = 0; q < 4; ++q) pool[nt] += fmaxf(acc[q], 0.f);
            } else {
                #pragma unroll
                for (int q = 0; q < 4; ++q)
                    pool[nt] += (rbase + q < ns) ? fmaxf(acc[q], 0.f) : 0.f;
            }
        }
    }

    // reduce across the 4 k-groups (rows) and publish pooled
    #pragma unroll
    for (int nt = 0; nt < 16; ++nt) {
        float p = pool[nt];
        p += __shfl_xor(p, 16);
        p += __shfl_xor(p, 32);
        pool[nt] = p;
    }
    __syncthreads();    // all waves past h-phase reads; s_atom alias now safe
    if (lg == 0) {
        #pragma unroll
        for (int nt = 0; nt < 16; ++nt) s_pool[wb + nt * 16 + lr] = pool[nt];
    }
    __syncthreads();

    // ---- d1 = relu(pooled @ W1 + b1) ----
    {
        const int m = t & 31, part = t >> 5;
        float s = 0.f;
        const int j0 = part * 128;
        for (int j = j0; j < j0 + 128; ++j) s += s_pool[j] * W1[j * 32 + m];
        s_red[part * 32 + m] = s;
    }
    __syncthreads();
    if (t < 32) {
        float s = b1[t];
        #pragma unroll
        for (int p = 0; p < 8; ++p) s += s_red[p * 32 + t];
        s_d1[t] = fmaxf(s, 0.f);
    }
    __syncthreads();

    // ---- d5 = relu(d1 @ W5 + b5) ----
    if (t < 16) {
        float s = b5[t];
        #pragma unroll
        for (int m = 0; m < 32; ++m) s += s_d1[m] * W5[m * 16 + t];
        s_d5[t] = fmaxf(s, 0.f);
    }
    __syncthreads();

    // ---- model_var, merge, output ----
    if (t == 0) {
        float mv = b6[0];
        #pragma unroll
        for (int m = 0; m < 16; ++m) mv += s_d5[m] * W6[m];
        float o = b7[0] + W7[0] * mv;
        #pragma unroll
        for (int i = 0; i < NPHYS; ++i) o += W7[i + 1] * s_phys[i];
        out[(size_t)b * 16] = o;
    }
    if (t < NPHYS) out[(size_t)b * 16 + 1 + t] = s_phys[t];
}

extern "C" void kernel_launch(void* const* d_in, const int* in_sizes, int n_in,
                              void* d_out, int out_size, void* d_ws, size_t ws_size,
                              hipStream_t stream) {
    const float* inputs = (const float*)d_in[0];
    const int*   i_s    = (const int*)d_in[1];
    const float* W_self = (const float*)d_in[2];
    const float* W_nei  = (const float*)d_in[3];
    const float* b_r    = (const float*)d_in[4];
    const float* Wc     = (const float*)d_in[5];
    const float* bc     = (const float*)d_in[6];
    const float* W1     = (const float*)d_in[7];
    const float* b1     = (const float*)d_in[8];
    const float* W5     = (const float*)d_in[9];
    const float* b5     = (const float*)d_in[10];
    const float* W6     = (const float*)d_in[11];
    const float* b6     = (const float*)d_in[12];
    const float* W7     = (const float*)d_in[13];
    const float* b7     = (const float*)d_in[14];
    float* out = (float*)d_out;

    const int B = in_sizes[1];   // 1024
    pggcn_kernel<<<B, BLOCK, 0, stream>>>(inputs, i_s, W_self, W_nei, b_r, Wc, bc,
                                          W1, b1, W5, b5, W6, b6, W7, b7, out);
}

// Round 3
// 89.102 us; speedup vs baseline: 2.0774x; 2.0774x over previous
//
#include <hip/hip_runtime.h>
#include <hip/hip_bf16.h>

#define A_DIM 200
#define F_DIM 53
#define NAF 38
#define NPHYS 15
#define R_OUT 20
#define C_OUT 1024
#define BLOCK 256
#define HPAD 40      // padded K stride of s_h in bf16 elems (zeros at 20..31)
#define MPAD 208     // padded M (13 tiles of 16)
#define KP 24        // padded K stride of wcT in d_ws (zeros at 20..23)

typedef __attribute__((ext_vector_type(8))) short short8;
typedef __attribute__((ext_vector_type(4))) float floatx4;

__device__ __forceinline__ float bf_lo(uint w) { return __uint_as_float(w << 16); }
__device__ __forceinline__ float bf_hi(uint w) { return __uint_as_float(w & 0xffff0000u); }
__device__ __forceinline__ ushort f2bf(float f) {
    union { __hip_bfloat16 h; ushort u; } cv;
    cv.h = __float2bfloat16(f);   // RNE
    return cv.u;
}

// ---- pre-kernel: Wc (20,1024) fp32 -> wcT (1024,24) bf16, k>=20 zeroed ----
__global__ void wc_prep(const float* __restrict__ Wc, ushort* __restrict__ wcT) {
    const int i = blockIdx.x * 256 + threadIdx.x;
    if (i >= C_OUT * KP) return;
    const int col = i / KP;
    const int k   = i - col * KP;
    const float v = (k < R_OUT) ? Wc[k * C_OUT + col] : 0.f;
    wcT[i] = f2bf(v);
}

template <bool USE_WS>
__global__ __launch_bounds__(BLOCK, 3) void pggcn_kernel(
    const float* __restrict__ inputs,
    const int*   __restrict__ i_s,
    const float* __restrict__ W_self,
    const float* __restrict__ W_nei,
    const float* __restrict__ b_r,
    const float* __restrict__ Wc,
    const float* __restrict__ bc,
    const float* __restrict__ W1,
    const float* __restrict__ b1,
    const float* __restrict__ W5,
    const float* __restrict__ b5,
    const float* __restrict__ W6,
    const float* __restrict__ b6,
    const float* __restrict__ W7,
    const float* __restrict__ b7,
    const ushort* __restrict__ wcT,   // (1024,24) bf16 in d_ws
    float* __restrict__ out)
{
    __shared__ __align__(16) ushort s_atom[A_DIM * NAF];   // 15200 B (aliased later)
    __shared__ __align__(16) ushort s_h[MPAD * HPAD];      // 16640 B
    __shared__ float s_wself[NAF * R_OUT];
    __shared__ float s_aggp[6 * NAF];
    __shared__ float s_agg[NAF];
    __shared__ float s_hnei[R_OUT];
    __shared__ float s_phys[NPHYS];

    float* s_pool = (float*)s_atom;
    float* s_red  = (float*)s_atom + C_OUT;
    float* s_d1   = (float*)s_atom + C_OUT + 256;
    float* s_d5   = (float*)s_atom + C_OUT + 288;

    const int b    = blockIdx.x;
    const int t    = threadIdx.x;
    const int lane = t & 63;
    const int wv   = t >> 6;
    const int wb   = wv * 256;
    const int lr   = lane & 15;
    const int lg   = lane >> 4;
    const int ns   = i_s[b];
    const float* in_b = inputs + (size_t)b * (A_DIM * F_DIM);

    // ---- stage W_self, physics, active atom rows (bf16) ----
    for (int i = t; i < NAF * R_OUT; i += BLOCK) s_wself[i] = W_self[i];
    if (t < NPHYS) s_phys[t] = in_b[NAF + t];
    const int tot = ns * NAF;
    for (int i = t; i < tot; i += BLOCK) {
        const int r = i / NAF;
        const int f = i - r * NAF;
        s_atom[i] = f2bf(in_b[r * F_DIM + f]);
    }
    __syncthreads();

    // ---- agg[f] = sum_{r<ns} atom[r][f] ----
    if (t < 6 * NAF) {
        const int f = t % NAF, g = t / NAF;
        float s = 0.f;
        for (int r = g; r < ns; r += 6)
            s += __uint_as_float((uint)s_atom[r * NAF + f] << 16);
        s_aggp[t] = s;
    }
    __syncthreads();
    if (t < NAF) {
        float s = 0.f;
        #pragma unroll
        for (int g = 0; g < 6; ++g) s += s_aggp[g * NAF + t];
        s_agg[t] = s;
    }
    __syncthreads();

    // ---- hnei[j] = agg @ W_nei + b_r ----
    if (t < R_OUT) {
        float s = b_r[t];
        #pragma unroll
        for (int f = 0; f < NAF; ++f) s += s_agg[f] * W_nei[f * R_OUT + t];
        s_hnei[t] = s;
    }
    __syncthreads();

    // ---- h rows -> s_h (bf16, K-padded with zeros) ----
    {
        const int j  = t % R_OUT;
        const int rg = t / R_OUT;    // 0..12 (240 active)
        if (rg < 12) {
            float wcol[NAF];
            #pragma unroll
            for (int f = 0; f < NAF; ++f) wcol[f] = s_wself[f * R_OUT + j];
            const float hn = s_hnei[j];
            for (int r = rg; r < ns; r += 12) {
                const uint* arow = (const uint*)&s_atom[r * NAF];
                float acc = hn;
                #pragma unroll
                for (int q = 0; q < NAF / 2; ++q) {
                    const uint w = arow[q];
                    acc += bf_lo(w) * wcol[2 * q];
                    acc += bf_hi(w) * wcol[2 * q + 1];
                }
                s_h[r * HPAD + j] = f2bf(fmaxf(acc, 0.f));
                if (j < 12) s_h[r * HPAD + R_OUT + j] = 0;   // zero k=20..31
            }
        }
    }

    // ---- B-fragments of Wc (bf16) + bias (deferred: no overlap with wcol[]) ----
    // B layout for mfma_f32_16x16x32_bf16: col = lane&15, k = (lane>>4)*8 + j
    short8 bfr[16];
    float  bcv[16];
    #pragma unroll
    for (int nt = 0; nt < 16; ++nt) {
        const int col = wb + nt * 16 + lr;
        bcv[nt] = bc[col];
        if (USE_WS) {
            if (lg < 3) {
                bfr[nt] = *(const short8*)&wcT[col * KP + lg * 8];
            } else {
                bfr[nt] = short8{0,0,0,0,0,0,0,0};
            }
        } else {
            const int kbase = lg * 8;
            #pragma unroll
            for (int j = 0; j < 8; ++j) {
                const int k = kbase + j;
                bfr[nt][j] = (short)((k < R_OUT) ? f2bf(Wc[k * C_OUT + col]) : 0);
            }
        }
    }
    __syncthreads();   // h ready; gather latency hides under barrier

    // ---- main: pooled = sum_rows relu(h @ Wc + bc), MFMA ----
    float pool[16];
    #pragma unroll
    for (int nt = 0; nt < 16; ++nt) pool[nt] = 0.f;

    const int nmt = (ns + 15) >> 4;
    for (int mt = 0; mt < nmt; ++mt) {
        const short8 af = *(const short8*)&s_h[(mt * 16 + lr) * HPAD + lg * 8];
        const bool full = (mt * 16 + 16 <= ns);
        const int rbase = mt * 16 + (lg << 2);
        #pragma unroll
        for (int nt = 0; nt < 16; ++nt) {
            floatx4 acc = { bcv[nt], bcv[nt], bcv[nt], bcv[nt] };
            acc = __builtin_amdgcn_mfma_f32_16x16x32_bf16(af, bfr[nt], acc, 0, 0, 0);
            if (full) {
                #pragma unroll
                for (int q = 0; q < 4; ++q) pool[nt] += fmaxf(acc[q], 0.f);
            } else {
                #pragma unroll
                for (int q = 0; q < 4; ++q)
                    pool[nt] += (rbase + q < ns) ? fmaxf(acc[q], 0.f) : 0.f;
            }
        }
    }

    #pragma unroll
    for (int nt = 0; nt < 16; ++nt) {
        float p = pool[nt];
        p += __shfl_xor(p, 16);
        p += __shfl_xor(p, 32);
        pool[nt] = p;
    }
    __syncthreads();   // everyone past s_atom reads; alias region safe
    if (lg == 0) {
        #pragma unroll
        for (int nt = 0; nt < 16; ++nt) s_pool[wb + nt * 16 + lr] = pool[nt];
    }
    __syncthreads();

    // ---- d1 = relu(pooled @ W1 + b1) ----
    {
        const int m = t & 31, part = t >> 5;
        float s = 0.f;
        const int j0 = part * 128;
        for (int j = j0; j < j0 + 128; ++j) s += s_pool[j] * W1[j * 32 + m];
        s_red[part * 32 + m] = s;
    }
    __syncthreads();
    if (t < 32) {
        float s = b1[t];
        #pragma unroll
        for (int p = 0; p < 8; ++p) s += s_red[p * 32 + t];
        s_d1[t] = fmaxf(s, 0.f);
    }
    __syncthreads();

    // ---- d5 = relu(d1 @ W5 + b5) ----
    if (t < 16) {
        float s = b5[t];
        #pragma unroll
        for (int m = 0; m < 32; ++m) s += s_d1[m] * W5[m * 16 + t];
        s_d5[t] = fmaxf(s, 0.f);
    }
    __syncthreads();

    // ---- model_var, merge, output ----
    if (t == 0) {
        float mv = b6[0];
        #pragma unroll
        for (int m = 0; m < 16; ++m) mv += s_d5[m] * W6[m];
        float o = b7[0] + W7[0] * mv;
        #pragma unroll
        for (int i = 0; i < NPHYS; ++i) o += W7[i + 1] * s_phys[i];
        out[(size_t)b * 16] = o;
    }
    if (t < NPHYS) out[(size_t)b * 16 + 1 + t] = s_phys[t];
}

extern "C" void kernel_launch(void* const* d_in, const int* in_sizes, int n_in,
                              void* d_out, int out_size, void* d_ws, size_t ws_size,
                              hipStream_t stream) {
    const float* inputs = (const float*)d_in[0];
    const int*   i_s    = (const int*)d_in[1];
    const float* W_self = (const float*)d_in[2];
    const float* W_nei  = (const float*)d_in[3];
    const float* b_r    = (const float*)d_in[4];
    const float* Wc     = (const float*)d_in[5];
    const float* bc     = (const float*)d_in[6];
    const float* W1     = (const float*)d_in[7];
    const float* b1     = (const float*)d_in[8];
    const float* W5     = (const float*)d_in[9];
    const float* b5     = (const float*)d_in[10];
    const float* W6     = (const float*)d_in[11];
    const float* b6     = (const float*)d_in[12];
    const float* W7     = (const float*)d_in[13];
    const float* b7     = (const float*)d_in[14];
    float* out = (float*)d_out;

    const int B = in_sizes[1];   // 1024
    const bool use_ws = (ws_size >= (size_t)(C_OUT * KP * sizeof(ushort)));
    ushort* wcT = (ushort*)d_ws;

    if (use_ws) {
        wc_prep<<<(C_OUT * KP + 255) / 256, 256, 0, stream>>>(Wc, wcT);
        pggcn_kernel<true><<<B, BLOCK, 0, stream>>>(inputs, i_s, W_self, W_nei, b_r,
            Wc, bc, W1, b1, W5, b5, W6, b6, W7, b7, wcT, out);
    } else {
        pggcn_kernel<false><<<B, BLOCK, 0, stream>>>(inputs, i_s, W_self, W_nei, b_r,
            Wc, bc, W1, b1, W5, b5, W6, b6, W7, b7, wcT, out);
    }
}